// Round 8
// baseline (153.029 us; speedup 1.0000x reference)
//
#include <hip/hip_runtime.h>
#include <hip/hip_bf16.h>
#include <math.h>

#define NNODES 100000
#define NEDGES 600000
#define IN 128
#define HD 128   // NUM_HEADS * OUT_DIM
#define NH 8
#define NEG_SLOPE 0.2f
#define RG_TOTAL (NNODES / 16)   // 6250 row-groups of 16 (exact)
#define NFRAG 36                 // 4 K-steps * 9 col-tiles
#define CT_ALL 9                 // 8 z col-tiles + 1 [el|er] tile

typedef __attribute__((ext_vector_type(8))) short short8v;
typedef __attribute__((ext_vector_type(4))) float f32x4;

__device__ inline unsigned short f2bf(float f) {
    unsigned u = __float_as_uint(f);
    unsigned r = (u + 0x7fff + ((u >> 16) & 1)) >> 16;
    return (unsigned short)r;
}
__device__ inline float bflo(unsigned v) { return __uint_as_float(v << 16); }
__device__ inline float bfhi(unsigned v) { return __uint_as_float(v & 0xffff0000u); }

// ---------------- pack W (+ fused Wl/Wr logit columns) into MFMA fragment order ----------------
// fragment map (identical for A- and B-operand roles): lane&15 = non-k index,
// elems j = 8 consecutive k at k0=(lane>>4)*8
__global__ __launch_bounds__(256) void k_pack(
    const float* __restrict__ W, const float* __restrict__ attn_l, const float* __restrict__ attn_r,
    short8v* __restrict__ Wb)
{
    int t = threadIdx.x;
    for (int slot = t; slot < NFRAG * 64; slot += 256) {
        int f = slot >> 6, lane = slot & 63;
        int ks = f / CT_ALL, ct = f % CT_ALL;
        int k0 = ks * 32 + (lane >> 4) * 8;
        short8v v;
        if (ct < 8) {
            int col = ct * 16 + (lane & 15);
            #pragma unroll
            for (int j = 0; j < 8; ++j) v[j] = (short)f2bf(W[(k0 + j) * HD + col]);
        } else {
            int c = lane & 15;
            const float* av = (c < 8) ? attn_l : attn_r;
            int hh = c & 7;
            #pragma unroll
            for (int j = 0; j < 8; ++j) {
                int k = k0 + j;
                float s = 0.f;
                for (int d = 0; d < 16; ++d) s += W[k * HD + hh * 16 + d] * av[hh * 16 + d];
                v[j] = (short)f2bf(s);
            }
        }
        Wb[slot] = v;
    }
}

// ---------------- MFMA GEMM: z = h@W (bf16 out) + el/er ----------------
// OPERAND-SWAPPED: acc = mfma(Wfrag, hfrag) computes the transposed tile, so
// lane&15 = node row, (lane>>4)*4+reg = 4 CONSECUTIVE z-cols -> 8B dwordx2 stores.
__global__ __launch_bounds__(256) void k_gemm_mfma(
    const float* __restrict__ h, const short8v* __restrict__ Wb,
    unsigned short* __restrict__ z, float* __restrict__ el, float* __restrict__ er)
{
    __shared__ short8v Bs[NFRAG * 64];   // 36 KB
    const int tid = threadIdx.x;
    {
        const float4* srcp = (const float4*)Wb;
        float4* dstp = (float4*)Bs;
        for (int i = tid; i < NFRAG * 64; i += 256) dstp[i] = srcp[i];
    }
    __syncthreads();

    const int lane  = tid & 63;
    const int rowIn = lane & 15;    // node row within group
    const int kgrp  = lane >> 4;    // k-group for loads / col-group for C
    int wid = (blockIdx.x * 256 + tid) >> 6;
    const int nw = gridDim.x * 4;

    for (int rg = wid; rg < RG_TOTAL; rg += nw) {
        const int row0 = rg * 16;
        const float* hp = h + (size_t)(row0 + rowIn) * IN + kgrp * 8;

        short8v afr[4];
        #pragma unroll
        for (int ks = 0; ks < 4; ++ks) {
            float4 a0 = *(const float4*)(hp + ks * 32);
            float4 a1 = *(const float4*)(hp + ks * 32 + 4);
            short8v v;
            v[0] = (short)f2bf(a0.x); v[1] = (short)f2bf(a0.y);
            v[2] = (short)f2bf(a0.z); v[3] = (short)f2bf(a0.w);
            v[4] = (short)f2bf(a1.x); v[5] = (short)f2bf(a1.y);
            v[6] = (short)f2bf(a1.z); v[7] = (short)f2bf(a1.w);
            afr[ks] = v;
        }

        f32x4 acc[CT_ALL];
        #pragma unroll
        for (int ct = 0; ct < CT_ALL; ++ct) acc[ct] = (f32x4){0.f, 0.f, 0.f, 0.f};

        #pragma unroll
        for (int ks = 0; ks < 4; ++ks)
            #pragma unroll
            for (int ct = 0; ct < CT_ALL; ++ct)
                acc[ct] = __builtin_amdgcn_mfma_f32_16x16x32_bf16(
                    Bs[(ks * CT_ALL + ct) * 64 + lane], afr[ks], acc[ct], 0, 0, 0);

        // z store: row = row0+rowIn, cols ct*16 + kgrp*4 .. +3  (8B per lane per tile)
        const size_t zrow = (size_t)(row0 + rowIn) * HD;
        #pragma unroll
        for (int ct = 0; ct < 8; ++ct) {
            uint2 pk;
            pk.x = (unsigned)f2bf(acc[ct][0]) | ((unsigned)f2bf(acc[ct][1]) << 16);
            pk.y = (unsigned)f2bf(acc[ct][2]) | ((unsigned)f2bf(acc[ct][3]) << 16);
            *(uint2*)(z + zrow + ct * 16 + kgrp * 4) = pk;
        }

        // [el|er] tile: cols kgrp*4..+3 of [el(0-7)|er(8-15)] for row rowIn
        {
            float4 v = make_float4(acc[8][0], acc[8][1], acc[8][2], acc[8][3]);
            int row = row0 + rowIn;
            if (kgrp < 2) *(float4*)(el + row * NH + kgrp * 4) = v;
            else          *(float4*)(er + row * NH + (kgrp - 2) * 4) = v;
        }
    }
}

// ---------------- CSR build ----------------
__global__ void k_hist(const int* __restrict__ dst, int* __restrict__ cnt) {
    int e = blockIdx.x * blockDim.x + threadIdx.x;
    if (e >= NEDGES) return;
    atomicAdd(&cnt[dst[e]], 1);
}

__global__ __launch_bounds__(1024) void kscan1(const int* __restrict__ cnt,
                                               int* __restrict__ inc, int* __restrict__ bsum) {
    __shared__ int buf[2][1024];
    int t = threadIdx.x;
    int i = blockIdx.x * 1024 + t;
    int v = (i < NNODES) ? cnt[i] : 0;
    buf[0][t] = v; __syncthreads();
    int cur = 0;
    for (int off = 1; off < 1024; off <<= 1) {
        int nv = buf[cur][t];
        if (t >= off) nv += buf[cur][t - off];
        buf[cur ^ 1][t] = nv; __syncthreads();
        cur ^= 1;
    }
    if (i < NNODES) inc[i] = buf[cur][t];
    if (t == 1023) bsum[blockIdx.x] = buf[cur][1023];
}

__global__ __launch_bounds__(128) void kscan2(int* __restrict__ bsum, int n) {
    __shared__ int buf[2][128];
    int t = threadIdx.x;
    int v = (t < n) ? bsum[t] : 0;
    buf[0][t] = v; __syncthreads();
    int cur = 0;
    for (int off = 1; off < 128; off <<= 1) {
        int nv = buf[cur][t];
        if (t >= off) nv += buf[cur][t - off];
        buf[cur ^ 1][t] = nv; __syncthreads();
        cur ^= 1;
    }
    if (t < n) bsum[t] = buf[cur][t] - v;
}

__global__ __launch_bounds__(1024) void kscan3(const int* __restrict__ cnt, const int* __restrict__ inc,
                                               const int* __restrict__ bsum,
                                               int* __restrict__ offs, int* __restrict__ cursor) {
    int t = threadIdx.x;
    int i = blockIdx.x * 1024 + t;
    if (i < NNODES) {
        int ex = inc[i] - cnt[i] + bsum[blockIdx.x];
        offs[i] = ex;
        cursor[i] = ex;
    }
    if (i == 0) offs[NNODES] = NEDGES;
}

__global__ void k_scatter(const int* __restrict__ src, const int* __restrict__ dst,
                          int* __restrict__ cursor, int* __restrict__ esrc) {
    int e = blockIdx.x * blockDim.x + threadIdx.x;
    if (e >= NEDGES) return;
    int d = dst[e];
    int pos = atomicAdd(&cursor[d], 1);
    esrc[pos] = src[e];
}

// ---------------- aggregate: one wave per node, batched-MLP gather ----------------
__global__ __launch_bounds__(256) void k_agg(
    const int* __restrict__ offs, const int* __restrict__ esrc,
    const float* __restrict__ el, const float* __restrict__ er,
    const unsigned short* __restrict__ z, const float* __restrict__ o,
    float* __restrict__ out)
{
    const int wid  = (blockIdx.x * blockDim.x + threadIdx.x) >> 6;
    const int lane = threadIdx.x & 63;
    if (wid >= NNODES) return;
    const int d = wid;
    const int p0 = offs[d];
    const int n  = offs[d + 1] - p0;
    const int hh = lane >> 3;
    const float el8 = el[d * NH + hh];

    float srun = 0.f, a0 = 0.f, a1 = 0.f;

    for (int c0 = 0; c0 < n; c0 += 64) {
        const int m = (n - c0 < 64) ? (n - c0) : 64;   // wave-uniform
        int sid = esrc[p0 + c0 + (lane < m ? lane : 0)];

        for (int b = 0; b < m; b += 8) {
            unsigned zb[8]; float erv[8];
            #pragma unroll
            for (int k = 0; k < 8; ++k) {
                int idx = (b + k < m) ? (b + k) : b;     // clamp tail to a live lane
                int s = __shfl(sid, idx, 64);
                erv[k] = er[s * NH + hh];
                zb[k]  = ((const unsigned*)(z + (size_t)s * HD))[lane];
            }
            #pragma unroll
            for (int k = 0; k < 8; ++k) {
                float ev = el8 + erv[k];
                ev = (ev >= 0.f) ? ev : NEG_SLOPE * ev;
                float ex = (b + k < m) ? __expf(ev) : 0.f;   // uniform select
                srun += ex;
                a0 = fmaf(ex, bflo(zb[k]), a0);
                a1 = fmaf(ex, bfhi(zb[k]), a1);
            }
        }
    }

    const size_t base = (size_t)d * HD + 2 * lane;
    float inv = (srun > 0.f) ? 1.f / srun : 0.f;
    float r0 = a0 * inv, r1 = a1 * inv;
    r0 = (r0 > 0.f) ? r0 : expm1f(r0);
    r1 = (r1 > 0.f) ? r1 : expm1f(r1);
    float2 ov = *(const float2*)(o + base);
    float2 res = make_float2(ov.x + r0, ov.y + r1);
    *(float2*)(out + base) = res;
}

extern "C" void kernel_launch(void* const* d_in, const int* in_sizes, int n_in,
                              void* d_out, int out_size, void* d_ws, size_t ws_size,
                              hipStream_t stream) {
    const float* h      = (const float*)d_in[0];
    const float* o      = (const float*)d_in[1];
    const float* W      = (const float*)d_in[2];
    const float* attn_l = (const float*)d_in[3];
    const float* attn_r = (const float*)d_in[4];
    const int*   src    = (const int*)d_in[5];
    const int*   dst    = (const int*)d_in[6];
    float* out = (float*)d_out;

    char* ws = (char*)d_ws;
    unsigned short* z = (unsigned short*)(ws);         // 25,600,000 B (bf16)
    float* el     = (float*)(ws + 25600000);           //  3,200,000
    float* er     = (float*)(ws + 28800000);           //  3,200,000
    int*   cnt    = (int*)  (ws + 32000000);           //    400,000
    int*   inc    = (int*)  (ws + 32400000);           //    400,000
    int*   offs   = (int*)  (ws + 32800000);           //    400,016
    int*   cursor = (int*)  (ws + 33200016);           //    400,000
    int*   bsum   = (int*)  (ws + 33600016);           //        512
    int*   esrc   = (int*)  (ws + 33600528);           //  2,400,000
    short8v* Wb   = (short8v*)(ws + 36000528);         //     36,864  (end ~36 MB)

    const int SCAN_BLOCKS = (NNODES + 1023) / 1024;    // 98

    hipMemsetAsync(cnt, 0, NNODES * sizeof(int), stream);

    k_pack<<<1, 256, 0, stream>>>(W, attn_l, attn_r, Wb);
    k_gemm_mfma<<<782, 256, 0, stream>>>(h, Wb, z, el, er);

    k_hist<<<(NEDGES + 255) / 256, 256, 0, stream>>>(dst, cnt);
    kscan1<<<SCAN_BLOCKS, 1024, 0, stream>>>(cnt, inc, bsum);
    kscan2<<<1, 128, 0, stream>>>(bsum, SCAN_BLOCKS);
    kscan3<<<SCAN_BLOCKS, 1024, 0, stream>>>(cnt, inc, bsum, offs, cursor);
    k_scatter<<<(NEDGES + 255) / 256, 256, 0, stream>>>(src, dst, cursor, esrc);

    k_agg<<<(NNODES * 64 + 255) / 256, 256, 0, stream>>>(offs, esrc, el, er, z, o, out);
}

// Round 9
// 140.487 us; speedup vs baseline: 1.0893x; 1.0893x over previous
//
#include <hip/hip_runtime.h>
#include <hip/hip_bf16.h>
#include <math.h>

#define NNODES 100000
#define NEDGES 600000
#define IN 128
#define HD 128   // NUM_HEADS * OUT_DIM
#define NH 8
#define NEG_SLOPE 0.2f
#define RG_TOTAL (NNODES / 16)   // 6250 row-groups of 16 (exact)
#define NFRAG 36                 // 4 K-steps * 9 col-tiles
#define CT_ALL 9                 // 8 z col-tiles + 1 [el|er] tile
#define NPAD 100352              // 98*1024, padded node count for scan
#define SCAN_BLOCKS 98
#define PACK_BLOCKS 9
#define HIST_BLOCKS ((NEDGES + 255) / 256)
#define GEMM_BLOCKS 782

typedef __attribute__((ext_vector_type(8))) short short8v;
typedef __attribute__((ext_vector_type(4))) float f32x4;

__device__ inline unsigned short f2bf(float f) {
    unsigned u = __float_as_uint(f);
    unsigned r = (u + 0x7fff + ((u >> 16) & 1)) >> 16;
    return (unsigned short)r;
}
__device__ inline float bflo(unsigned v) { return __uint_as_float(v << 16); }
__device__ inline float bfhi(unsigned v) { return __uint_as_float(v & 0xffff0000u); }

// ---------------- FAT: W-pack (blocks 0..8) + dst histogram (blocks 9..) ----------------
__global__ __launch_bounds__(256) void k_pack_hist(
    const float* __restrict__ W, const float* __restrict__ attn_l, const float* __restrict__ attn_r,
    short8v* __restrict__ Wb,
    const int* __restrict__ dst, int* __restrict__ cnt)
{
    const int tid = threadIdx.x;
    if (blockIdx.x < PACK_BLOCKS) {
        int slot = blockIdx.x * 256 + tid;   // 2304 slots exactly
        int f = slot >> 6, lane = slot & 63;
        int ks = f / CT_ALL, ct = f % CT_ALL;
        int k0 = ks * 32 + (lane >> 4) * 8;
        short8v v;
        if (ct < 8) {
            int col = ct * 16 + (lane & 15);
            #pragma unroll
            for (int j = 0; j < 8; ++j) v[j] = (short)f2bf(W[(k0 + j) * HD + col]);
        } else {
            int c = lane & 15;
            const float* av = (c < 8) ? attn_l : attn_r;
            int hh = c & 7;
            #pragma unroll
            for (int j = 0; j < 8; ++j) {
                int k = k0 + j;
                float s = 0.f;
                for (int d = 0; d < 16; ++d) s += W[k * HD + hh * 16 + d] * av[hh * 16 + d];
                v[j] = (short)f2bf(s);
            }
        }
        Wb[slot] = v;
    } else {
        int e = (blockIdx.x - PACK_BLOCKS) * 256 + tid;
        if (e < NEDGES) atomicAdd(&cnt[dst[e]], 1);
    }
}

// ---------------- FAT: scan1 (blocks 0..97) + MFMA GEMM (blocks 98..879) ----------------
// scan1: 256 thr x int4 -> 1024 counts/block; writes per-element inclusive-in-block + block sum
// gemm (operand-swapped): lane&15 = node row, (lane>>4)*4+reg = 4 consecutive z-cols
__global__ __launch_bounds__(256) void k_gemm_scan1(
    const float* __restrict__ h, const short8v* __restrict__ Wb,
    unsigned short* __restrict__ z, float* __restrict__ el, float* __restrict__ er,
    const int* __restrict__ cnt, int* __restrict__ inc, int* __restrict__ bsum)
{
    __shared__ short8v Bs[NFRAG * 64];   // 36 KB (gemm)
    __shared__ int sd[2][256];           //  2 KB (scan)
    const int tid = threadIdx.x;

    if (blockIdx.x < SCAN_BLOCKS) {
        int gid4 = blockIdx.x * 256 + tid;
        int4 v = ((const int4*)cnt)[gid4];
        int s1 = v.x + v.y, s2 = s1 + v.z, s3 = s2 + v.w;
        sd[0][tid] = s3; __syncthreads();
        int cur = 0;
        for (int off = 1; off < 256; off <<= 1) {
            int nv = sd[cur][tid] + (tid >= off ? sd[cur][tid - off] : 0);
            sd[cur ^ 1][tid] = nv; __syncthreads();
            cur ^= 1;
        }
        int incl = sd[cur][tid];
        int eb = incl - s3;   // exclusive base for this thread's 4 elements
        int4 w = make_int4(eb + v.x, eb + s1, eb + s2, eb + s3);
        ((int4*)inc)[gid4] = w;
        if (tid == 255) bsum[blockIdx.x] = incl;
        return;
    }

    // ---- gemm ----
    {
        const float4* srcp = (const float4*)Wb;
        float4* dstp = (float4*)Bs;
        for (int i = tid; i < NFRAG * 64; i += 256) dstp[i] = srcp[i];
    }
    __syncthreads();

    const int lane  = tid & 63;
    const int rowIn = lane & 15;
    const int kgrp  = lane >> 4;
    int wid = ((blockIdx.x - SCAN_BLOCKS) * 256 + tid) >> 6;
    const int nw = GEMM_BLOCKS * 4;

    for (int rg = wid; rg < RG_TOTAL; rg += nw) {
        const int row0 = rg * 16;
        const float* hp = h + (size_t)(row0 + rowIn) * IN + kgrp * 8;

        short8v afr[4];
        #pragma unroll
        for (int ks = 0; ks < 4; ++ks) {
            float4 a0 = *(const float4*)(hp + ks * 32);
            float4 a1 = *(const float4*)(hp + ks * 32 + 4);
            short8v v;
            v[0] = (short)f2bf(a0.x); v[1] = (short)f2bf(a0.y);
            v[2] = (short)f2bf(a0.z); v[3] = (short)f2bf(a0.w);
            v[4] = (short)f2bf(a1.x); v[5] = (short)f2bf(a1.y);
            v[6] = (short)f2bf(a1.z); v[7] = (short)f2bf(a1.w);
            afr[ks] = v;
        }

        f32x4 acc[CT_ALL];
        #pragma unroll
        for (int ct = 0; ct < CT_ALL; ++ct) acc[ct] = (f32x4){0.f, 0.f, 0.f, 0.f};

        #pragma unroll
        for (int ks = 0; ks < 4; ++ks)
            #pragma unroll
            for (int ct = 0; ct < CT_ALL; ++ct)
                acc[ct] = __builtin_amdgcn_mfma_f32_16x16x32_bf16(
                    Bs[(ks * CT_ALL + ct) * 64 + lane], afr[ks], acc[ct], 0, 0, 0);

        const size_t zrow = (size_t)(row0 + rowIn) * HD;
        #pragma unroll
        for (int ct = 0; ct < 8; ++ct) {
            uint2 pk;
            pk.x = (unsigned)f2bf(acc[ct][0]) | ((unsigned)f2bf(acc[ct][1]) << 16);
            pk.y = (unsigned)f2bf(acc[ct][2]) | ((unsigned)f2bf(acc[ct][3]) << 16);
            *(uint2*)(z + zrow + ct * 16 + kgrp * 4) = pk;
        }
        {
            float4 v = make_float4(acc[8][0], acc[8][1], acc[8][2], acc[8][3]);
            int row = row0 + rowIn;
            if (kgrp < 2) *(float4*)(el + row * NH + kgrp * 4) = v;
            else          *(float4*)(er + row * NH + (kgrp - 2) * 4) = v;
        }
    }
}

// ---------------- merged scan2+scan3: every block scans the 98 block sums ----------------
__global__ __launch_bounds__(256) void kscan23(
    const int* __restrict__ cnt, const int* __restrict__ inc, const int* __restrict__ bsum,
    int* __restrict__ offs, int* __restrict__ cursor)
{
    __shared__ int bs[2][128];
    const int tid = threadIdx.x;
    if (tid < 128) bs[0][tid] = (tid < SCAN_BLOCKS) ? bsum[tid] : 0;
    __syncthreads();
    int cur = 0;
    for (int off = 1; off < 128; off <<= 1) {
        if (tid < 128) {
            int nv = bs[cur][tid] + (tid >= off ? bs[cur][tid - off] : 0);
            bs[cur ^ 1][tid] = nv;
        }
        __syncthreads();
        cur ^= 1;
    }
    const int base = (blockIdx.x == 0) ? 0 : bs[cur][blockIdx.x - 1];

    int gid4 = blockIdx.x * 256 + tid;
    int4 c = ((const int4*)cnt)[gid4];
    int4 ic = ((const int4*)inc)[gid4];
    int i0 = gid4 * 4;
    int ex[4] = { base + ic.x - c.x, base + ic.y - c.y, base + ic.z - c.z, base + ic.w - c.w };
    #pragma unroll
    for (int j = 0; j < 4; ++j) {
        int i = i0 + j;
        if (i < NNODES) { offs[i] = ex[j]; cursor[i] = ex[j]; }
        else if (i == NNODES) offs[i] = NEDGES;
    }
}

__global__ void k_scatter(const int* __restrict__ src, const int* __restrict__ dst,
                          int* __restrict__ cursor, int* __restrict__ esrc) {
    int e = blockIdx.x * blockDim.x + threadIdx.x;
    if (e >= NEDGES) return;
    int d = dst[e];
    int pos = atomicAdd(&cursor[d], 1);
    esrc[pos] = src[e];
}

// ---------------- aggregate: one wave per node, batched-MLP gather ----------------
__global__ __launch_bounds__(256) void k_agg(
    const int* __restrict__ offs, const int* __restrict__ esrc,
    const float* __restrict__ el, const float* __restrict__ er,
    const unsigned short* __restrict__ z, const float* __restrict__ o,
    float* __restrict__ out)
{
    const int wid  = (blockIdx.x * blockDim.x + threadIdx.x) >> 6;
    const int lane = threadIdx.x & 63;
    if (wid >= NNODES) return;
    const int d = wid;
    const int p0 = offs[d];
    const int n  = offs[d + 1] - p0;
    const int hh = lane >> 3;
    const float el8 = el[d * NH + hh];

    // hoist o load: overlap its latency with the gather loop
    const size_t base = (size_t)d * HD + 2 * lane;
    const float2 ov = *(const float2*)(o + base);

    float srun = 0.f, a0 = 0.f, a1 = 0.f;

    for (int c0 = 0; c0 < n; c0 += 64) {
        const int m = (n - c0 < 64) ? (n - c0) : 64;   // wave-uniform
        int sid = esrc[p0 + c0 + (lane < m ? lane : 0)];

        for (int b = 0; b < m; b += 8) {
            unsigned zb[8]; float erv[8];
            #pragma unroll
            for (int k = 0; k < 8; ++k) {
                int idx = (b + k < m) ? (b + k) : b;     // clamp tail to a live lane
                int s = __shfl(sid, idx, 64);
                erv[k] = er[s * NH + hh];
                zb[k]  = ((const unsigned*)(z + (size_t)s * HD))[lane];
            }
            #pragma unroll
            for (int k = 0; k < 8; ++k) {
                float ev = el8 + erv[k];
                ev = (ev >= 0.f) ? ev : NEG_SLOPE * ev;
                float ex = (b + k < m) ? __expf(ev) : 0.f;   // uniform select
                srun += ex;
                a0 = fmaf(ex, bflo(zb[k]), a0);
                a1 = fmaf(ex, bfhi(zb[k]), a1);
            }
        }
    }

    float inv = (srun > 0.f) ? 1.f / srun : 0.f;
    float r0 = a0 * inv, r1 = a1 * inv;
    r0 = (r0 > 0.f) ? r0 : expm1f(r0);
    r1 = (r1 > 0.f) ? r1 : expm1f(r1);
    *(float2*)(out + base) = make_float2(ov.x + r0, ov.y + r1);
}

extern "C" void kernel_launch(void* const* d_in, const int* in_sizes, int n_in,
                              void* d_out, int out_size, void* d_ws, size_t ws_size,
                              hipStream_t stream) {
    const float* h      = (const float*)d_in[0];
    const float* o      = (const float*)d_in[1];
    const float* W      = (const float*)d_in[2];
    const float* attn_l = (const float*)d_in[3];
    const float* attn_r = (const float*)d_in[4];
    const int*   src    = (const int*)d_in[5];
    const int*   dst    = (const int*)d_in[6];
    float* out = (float*)d_out;

    char* ws = (char*)d_ws;
    unsigned short* z = (unsigned short*)(ws);         // 25,600,000 B (bf16)
    float* el     = (float*)(ws + 25600000);           //  3,200,000
    float* er     = (float*)(ws + 28800000);           //  3,200,000
    int*   cnt    = (int*)  (ws + 32000000);           //    401,408 (NPAD ints)
    int*   inc    = (int*)  (ws + 32401408);           //    401,408
    int*   offs   = (int*)  (ws + 32802816);           //    400,016
    int*   cursor = (int*)  (ws + 33202832);           //    400,000
    int*   bsum   = (int*)  (ws + 33602832);           //        512
    int*   esrc   = (int*)  (ws + 33603344);           //  2,400,000
    short8v* Wb   = (short8v*)(ws + 36003344);         //     36,864  (end ~36.04 MB)

    hipMemsetAsync(cnt, 0, NPAD * sizeof(int), stream);

    k_pack_hist<<<PACK_BLOCKS + HIST_BLOCKS, 256, 0, stream>>>(W, attn_l, attn_r, Wb, dst, cnt);
    k_gemm_scan1<<<SCAN_BLOCKS + GEMM_BLOCKS, 256, 0, stream>>>(h, Wb, z, el, er, cnt, inc, bsum);
    kscan23<<<SCAN_BLOCKS, 256, 0, stream>>>(cnt, inc, bsum, offs, cursor);
    k_scatter<<<(NEDGES + 255) / 256, 256, 0, stream>>>(src, dst, cursor, esrc);
    k_agg<<<(NNODES * 64 + 255) / 256, 256, 0, stream>>>(offs, esrc, el, er, z, o, out);
}

// Round 10
// 138.562 us; speedup vs baseline: 1.1044x; 1.0139x over previous
//
#include <hip/hip_runtime.h>
#include <hip/hip_bf16.h>
#include <math.h>

#define NNODES 100000
#define NEDGES 600000
#define IN 128
#define HD 128   // NUM_HEADS * OUT_DIM
#define NH 8
#define NEG_SLOPE 0.2f
#define RG_TOTAL (NNODES / 16)   // 6250 row-groups of 16 (exact)
#define NFRAG 36                 // 4 K-steps * 9 col-tiles
#define CT_ALL 9                 // 8 z col-tiles + 1 [el|er] tile
#define NPAD 100352              // 98*1024, padded node count for scan
#define SCAN_BLOCKS 98
#define PACK_BLOCKS 9
#define HIST_BLOCKS ((NEDGES + 255) / 256)
#define GEMM_BLOCKS 782

typedef __attribute__((ext_vector_type(8))) short short8v;
typedef __attribute__((ext_vector_type(4))) float f32x4;

__device__ inline unsigned short f2bf(float f) {
    unsigned u = __float_as_uint(f);
    unsigned r = (u + 0x7fff + ((u >> 16) & 1)) >> 16;
    return (unsigned short)r;
}
__device__ inline float bflo(unsigned v) { return __uint_as_float(v << 16); }
__device__ inline float bfhi(unsigned v) { return __uint_as_float(v & 0xffff0000u); }

// ---------------- FAT: W-pack (blocks 0..8) + dst histogram (blocks 9..) ----------------
__global__ __launch_bounds__(256) void k_pack_hist(
    const float* __restrict__ W, const float* __restrict__ attn_l, const float* __restrict__ attn_r,
    short8v* __restrict__ Wb,
    const int* __restrict__ dst, int* __restrict__ cnt)
{
    const int tid = threadIdx.x;
    if (blockIdx.x < PACK_BLOCKS) {
        int slot = blockIdx.x * 256 + tid;   // 2304 slots exactly
        int f = slot >> 6, lane = slot & 63;
        int ks = f / CT_ALL, ct = f % CT_ALL;
        int k0 = ks * 32 + (lane >> 4) * 8;
        short8v v;
        if (ct < 8) {
            int col = ct * 16 + (lane & 15);
            #pragma unroll
            for (int j = 0; j < 8; ++j) v[j] = (short)f2bf(W[(k0 + j) * HD + col]);
        } else {
            int c = lane & 15;
            const float* av = (c < 8) ? attn_l : attn_r;
            int hh = c & 7;
            #pragma unroll
            for (int j = 0; j < 8; ++j) {
                int k = k0 + j;
                float s = 0.f;
                for (int d = 0; d < 16; ++d) s += W[k * HD + hh * 16 + d] * av[hh * 16 + d];
                v[j] = (short)f2bf(s);
            }
        }
        Wb[slot] = v;
    } else {
        int e = (blockIdx.x - PACK_BLOCKS) * 256 + tid;
        if (e < NEDGES) atomicAdd(&cnt[dst[e]], 1);
    }
}

// ---------------- FAT: scan1 (blocks 0..97) + MFMA GEMM (blocks 98..879) ----------------
__global__ __launch_bounds__(256) void k_gemm_scan1(
    const float* __restrict__ h, const short8v* __restrict__ Wb,
    unsigned short* __restrict__ z, float* __restrict__ el, float* __restrict__ er,
    const int* __restrict__ cnt, int* __restrict__ inc, int* __restrict__ bsum)
{
    __shared__ short8v Bs[NFRAG * 64];   // 36 KB (gemm)
    __shared__ int sd[2][256];           //  2 KB (scan)
    const int tid = threadIdx.x;

    if (blockIdx.x < SCAN_BLOCKS) {
        int gid4 = blockIdx.x * 256 + tid;
        int4 v = ((const int4*)cnt)[gid4];
        int s1 = v.x + v.y, s2 = s1 + v.z, s3 = s2 + v.w;
        sd[0][tid] = s3; __syncthreads();
        int cur = 0;
        for (int off = 1; off < 256; off <<= 1) {
            int nv = sd[cur][tid] + (tid >= off ? sd[cur][tid - off] : 0);
            sd[cur ^ 1][tid] = nv; __syncthreads();
            cur ^= 1;
        }
        int incl = sd[cur][tid];
        int eb = incl - s3;
        int4 w = make_int4(eb + v.x, eb + s1, eb + s2, eb + s3);
        ((int4*)inc)[gid4] = w;
        if (tid == 255) bsum[blockIdx.x] = incl;
        return;
    }

    // ---- gemm (operand-swapped MFMA) ----
    {
        const float4* srcp = (const float4*)Wb;
        float4* dstp = (float4*)Bs;
        for (int i = tid; i < NFRAG * 64; i += 256) dstp[i] = srcp[i];
    }
    __syncthreads();

    const int lane  = tid & 63;
    const int rowIn = lane & 15;
    const int kgrp  = lane >> 4;
    int wid = ((blockIdx.x - SCAN_BLOCKS) * 256 + tid) >> 6;
    const int nw = GEMM_BLOCKS * 4;

    for (int rg = wid; rg < RG_TOTAL; rg += nw) {
        const int row0 = rg * 16;
        const float* hp = h + (size_t)(row0 + rowIn) * IN + kgrp * 8;

        short8v afr[4];
        #pragma unroll
        for (int ks = 0; ks < 4; ++ks) {
            float4 a0 = *(const float4*)(hp + ks * 32);
            float4 a1 = *(const float4*)(hp + ks * 32 + 4);
            short8v v;
            v[0] = (short)f2bf(a0.x); v[1] = (short)f2bf(a0.y);
            v[2] = (short)f2bf(a0.z); v[3] = (short)f2bf(a0.w);
            v[4] = (short)f2bf(a1.x); v[5] = (short)f2bf(a1.y);
            v[6] = (short)f2bf(a1.z); v[7] = (short)f2bf(a1.w);
            afr[ks] = v;
        }

        f32x4 acc[CT_ALL];
        #pragma unroll
        for (int ct = 0; ct < CT_ALL; ++ct) acc[ct] = (f32x4){0.f, 0.f, 0.f, 0.f};

        #pragma unroll
        for (int ks = 0; ks < 4; ++ks)
            #pragma unroll
            for (int ct = 0; ct < CT_ALL; ++ct)
                acc[ct] = __builtin_amdgcn_mfma_f32_16x16x32_bf16(
                    Bs[(ks * CT_ALL + ct) * 64 + lane], afr[ks], acc[ct], 0, 0, 0);

        const size_t zrow = (size_t)(row0 + rowIn) * HD;
        #pragma unroll
        for (int ct = 0; ct < 8; ++ct) {
            uint2 pk;
            pk.x = (unsigned)f2bf(acc[ct][0]) | ((unsigned)f2bf(acc[ct][1]) << 16);
            pk.y = (unsigned)f2bf(acc[ct][2]) | ((unsigned)f2bf(acc[ct][3]) << 16);
            *(uint2*)(z + zrow + ct * 16 + kgrp * 4) = pk;
        }
        {
            float4 v = make_float4(acc[8][0], acc[8][1], acc[8][2], acc[8][3]);
            int row = row0 + rowIn;
            if (kgrp < 2) *(float4*)(el + row * NH + kgrp * 4) = v;
            else          *(float4*)(er + row * NH + (kgrp - 2) * 4) = v;
        }
    }
}

// ---------------- merged scan2+scan3 ----------------
__global__ __launch_bounds__(256) void kscan23(
    const int* __restrict__ cnt, const int* __restrict__ inc, const int* __restrict__ bsum,
    int* __restrict__ offs, int* __restrict__ cursor)
{
    __shared__ int bs[2][128];
    const int tid = threadIdx.x;
    if (tid < 128) bs[0][tid] = (tid < SCAN_BLOCKS) ? bsum[tid] : 0;
    __syncthreads();
    int cur = 0;
    for (int off = 1; off < 128; off <<= 1) {
        if (tid < 128) {
            int nv = bs[cur][tid] + (tid >= off ? bs[cur][tid - off] : 0);
            bs[cur ^ 1][tid] = nv;
        }
        __syncthreads();
        cur ^= 1;
    }
    const int base = (blockIdx.x == 0) ? 0 : bs[cur][blockIdx.x - 1];

    int gid4 = blockIdx.x * 256 + tid;
    int4 c = ((const int4*)cnt)[gid4];
    int4 ic = ((const int4*)inc)[gid4];
    int i0 = gid4 * 4;
    int ex[4] = { base + ic.x - c.x, base + ic.y - c.y, base + ic.z - c.z, base + ic.w - c.w };
    #pragma unroll
    for (int j = 0; j < 4; ++j) {
        int i = i0 + j;
        if (i < NNODES) { offs[i] = ex[j]; cursor[i] = ex[j]; }
        else if (i == NNODES) offs[i] = NEDGES;
    }
}

// 4-wide scatter
__global__ void k_scatter(const int* __restrict__ src, const int* __restrict__ dst,
                          int* __restrict__ cursor, int* __restrict__ esrc) {
    int e0 = (blockIdx.x * blockDim.x + threadIdx.x) * 4;
    if (e0 >= NEDGES) return;
    int4 s4 = *(const int4*)(src + e0);
    int4 d4 = *(const int4*)(dst + e0);
    int pos;
    pos = atomicAdd(&cursor[d4.x], 1); esrc[pos] = s4.x;
    pos = atomicAdd(&cursor[d4.y], 1); esrc[pos] = s4.y;
    pos = atomicAdd(&cursor[d4.z], 1); esrc[pos] = s4.z;
    pos = atomicAdd(&cursor[d4.w], 1); esrc[pos] = s4.w;
}

// ---------------- aggregate: one wave per node, 32 lanes per edge, 2 edges parallel ----------------
// lane = e2*32 + g; lane owns cols [g*4, g*4+4) (head hh = g>>2, uint2 of z).
__global__ __launch_bounds__(256) void k_agg(
    const int* __restrict__ offs, const int* __restrict__ esrc,
    const float* __restrict__ el, const float* __restrict__ er,
    const unsigned short* __restrict__ z, const float* __restrict__ o,
    float* __restrict__ out)
{
    const int wid  = (blockIdx.x * blockDim.x + threadIdx.x) >> 6;
    const int lane = threadIdx.x & 63;
    if (wid >= NNODES) return;
    const int d  = wid;
    const int p0 = offs[d];
    const int n  = offs[d + 1] - p0;
    const int g  = lane & 31;
    const int e2 = lane >> 5;
    const int hh = g >> 2;
    const float el8 = el[d * NH + hh];

    // hoisted o load (upper half duplicates lower's addresses -> coalescer dedups)
    const size_t obase = (size_t)d * HD + g * 4;
    const float4 ov = *(const float4*)(o + obase);

    float srun = 0.f;
    float4 acc = make_float4(0.f, 0.f, 0.f, 0.f);

    for (int c0 = 0; c0 < n; c0 += 64) {
        const int m = (n - c0 < 64) ? (n - c0) : 64;   // wave-uniform
        int sid = esrc[p0 + c0 + (lane < m ? lane : 0)];

        for (int b = 0; b < m; b += 8) {
            float erv[4]; uint2 zb[4];
            #pragma unroll
            for (int k = 0; k < 4; ++k) {
                int ei = b + k * 2 + e2;
                int eic = (ei < m) ? ei : 0;          // clamp to live lane
                int s = __shfl(sid, eic, 64);
                erv[k] = er[s * NH + hh];
                zb[k]  = *(const uint2*)(z + (size_t)s * HD + g * 4);
            }
            #pragma unroll
            for (int k = 0; k < 4; ++k) {
                int ei = b + k * 2 + e2;
                float ev = el8 + erv[k];
                ev = fmaxf(ev, NEG_SLOPE * ev);        // leaky relu in 2 ops
                float ex = (ei < m) ? __expf(ev) : 0.f;
                srun += ex;
                acc.x = fmaf(ex, bflo(zb[k].x), acc.x);
                acc.y = fmaf(ex, bfhi(zb[k].x), acc.y);
                acc.z = fmaf(ex, bflo(zb[k].y), acc.z);
                acc.w = fmaf(ex, bfhi(zb[k].y), acc.w);
            }
        }
    }

    // combine the two 32-lane halves
    srun  += __shfl_xor(srun, 32, 64);
    acc.x += __shfl_xor(acc.x, 32, 64);
    acc.y += __shfl_xor(acc.y, 32, 64);
    acc.z += __shfl_xor(acc.z, 32, 64);
    acc.w += __shfl_xor(acc.w, 32, 64);

    if (lane < 32) {
        float inv = (srun > 0.f) ? 1.f / srun : 0.f;
        float r0 = acc.x * inv, r1 = acc.y * inv, r2 = acc.z * inv, r3 = acc.w * inv;
        r0 = (r0 > 0.f) ? r0 : expm1f(r0);
        r1 = (r1 > 0.f) ? r1 : expm1f(r1);
        r2 = (r2 > 0.f) ? r2 : expm1f(r2);
        r3 = (r3 > 0.f) ? r3 : expm1f(r3);
        *(float4*)(out + obase) = make_float4(ov.x + r0, ov.y + r1, ov.z + r2, ov.w + r3);
    }
}

extern "C" void kernel_launch(void* const* d_in, const int* in_sizes, int n_in,
                              void* d_out, int out_size, void* d_ws, size_t ws_size,
                              hipStream_t stream) {
    const float* h      = (const float*)d_in[0];
    const float* o      = (const float*)d_in[1];
    const float* W      = (const float*)d_in[2];
    const float* attn_l = (const float*)d_in[3];
    const float* attn_r = (const float*)d_in[4];
    const int*   src    = (const int*)d_in[5];
    const int*   dst    = (const int*)d_in[6];
    float* out = (float*)d_out;

    char* ws = (char*)d_ws;
    unsigned short* z = (unsigned short*)(ws);         // 25,600,000 B (bf16)
    float* el     = (float*)(ws + 25600000);           //  3,200,000
    float* er     = (float*)(ws + 28800000);           //  3,200,000
    int*   cnt    = (int*)  (ws + 32000000);           //    401,408 (NPAD ints)
    int*   inc    = (int*)  (ws + 32401408);           //    401,408
    int*   offs   = (int*)  (ws + 32802816);           //    400,016
    int*   cursor = (int*)  (ws + 33202832);           //    400,000
    int*   bsum   = (int*)  (ws + 33602832);           //        512
    int*   esrc   = (int*)  (ws + 33603344);           //  2,400,000
    short8v* Wb   = (short8v*)(ws + 36003344);         //     36,864  (end ~36.04 MB)

    hipMemsetAsync(cnt, 0, NPAD * sizeof(int), stream);

    k_pack_hist<<<PACK_BLOCKS + HIST_BLOCKS, 256, 0, stream>>>(W, attn_l, attn_r, Wb, dst, cnt);
    k_gemm_scan1<<<SCAN_BLOCKS + GEMM_BLOCKS, 256, 0, stream>>>(h, Wb, z, el, er, cnt, inc, bsum);
    kscan23<<<SCAN_BLOCKS, 256, 0, stream>>>(cnt, inc, bsum, offs, cursor);
    k_scatter<<<(NEDGES / 4 + 255) / 256, 256, 0, stream>>>(src, dst, cursor, esrc);
    k_agg<<<(NNODES * 64 + 255) / 256, 256, 0, stream>>>(offs, esrc, el, er, z, o, out);
}

// Round 11
// 117.126 us; speedup vs baseline: 1.3065x; 1.1830x over previous
//
#include <hip/hip_runtime.h>
#include <hip/hip_bf16.h>
#include <math.h>

#define NNODES 100000
#define NEDGES 600000
#define IN 128
#define HD 128   // NUM_HEADS * OUT_DIM
#define NH 8
#define NEG_SLOPE 0.2f
#define RG_TOTAL (NNODES / 16)   // 6250 row-groups of 16 (exact)
#define NFRAG 36                 // 4 K-steps * 9 col-tiles
#define CT_ALL 9                 // 8 z col-tiles + 1 [el|er] tile
#define NPAD 100352              // 98*1024, padded node count for scan
#define SCAN_BLOCKS 98
#define PACK_BLOCKS 9
#define HIST4_BLOCKS ((NEDGES / 4 + 255) / 256)   // 586
#define GEMM_BLOCKS 782

typedef __attribute__((ext_vector_type(8))) short short8v;
typedef __attribute__((ext_vector_type(4))) float f32x4;

__device__ inline unsigned short f2bf(float f) {
    unsigned u = __float_as_uint(f);
    unsigned r = (u + 0x7fff + ((u >> 16) & 1)) >> 16;
    return (unsigned short)r;
}
__device__ inline float bflo(unsigned v) { return __uint_as_float(v << 16); }
__device__ inline float bfhi(unsigned v) { return __uint_as_float(v & 0xffff0000u); }
// packed f32x2 -> bf16x2 (RTNE), single HW instr on gfx950
__device__ inline unsigned cvtpk(float lo, float hi) {
    unsigned r;
    asm("v_cvt_pk_bf16_f32 %0, %1, %2" : "=v"(r) : "v"(lo), "v"(hi));
    return r;
}

// ---------------- FAT: W-pack (blocks 0..8) + dst histogram/rank (blocks 9..) ----------------
__global__ __launch_bounds__(256) void k_pack_hist(
    const float* __restrict__ W, const float* __restrict__ attn_l, const float* __restrict__ attn_r,
    short8v* __restrict__ Wb,
    const int* __restrict__ dst, int* __restrict__ cnt, int* __restrict__ rank)
{
    const int tid = threadIdx.x;
    if (blockIdx.x < PACK_BLOCKS) {
        int slot = blockIdx.x * 256 + tid;   // 2304 slots exactly
        int f = slot >> 6, lane = slot & 63;
        int ks = f / CT_ALL, ct = f % CT_ALL;
        int k0 = ks * 32 + (lane >> 4) * 8;
        short8v v;
        if (ct < 8) {
            int col = ct * 16 + (lane & 15);
            #pragma unroll
            for (int j = 0; j < 8; ++j) v[j] = (short)f2bf(W[(k0 + j) * HD + col]);
        } else {
            int c = lane & 15;
            const float* av = (c < 8) ? attn_l : attn_r;
            int hh = c & 7;
            #pragma unroll
            for (int j = 0; j < 8; ++j) {
                int k = k0 + j;
                float s = 0.f;
                for (int d = 0; d < 16; ++d) s += W[k * HD + hh * 16 + d] * av[hh * 16 + d];
                v[j] = (short)f2bf(s);
            }
        }
        Wb[slot] = v;
    } else {
        int e0 = ((blockIdx.x - PACK_BLOCKS) * 256 + tid) * 4;
        if (e0 < NEDGES) {
            int4 d4 = *(const int4*)(dst + e0);
            int4 r4;
            r4.x = atomicAdd(&cnt[d4.x], 1);
            r4.y = atomicAdd(&cnt[d4.y], 1);
            r4.z = atomicAdd(&cnt[d4.z], 1);
            r4.w = atomicAdd(&cnt[d4.w], 1);
            *(int4*)(rank + e0) = r4;   // rank = within-segment arrival order
        }
    }
}

// ---------------- FAT: scan1 (blocks 0..97) + MFMA GEMM (blocks 98..879) ----------------
__global__ __launch_bounds__(256) void k_gemm_scan1(
    const float* __restrict__ h, const short8v* __restrict__ Wb,
    unsigned short* __restrict__ z, float* __restrict__ el, float* __restrict__ er,
    const int* __restrict__ cnt, int* __restrict__ inc, int* __restrict__ bsum)
{
    __shared__ short8v Bs[NFRAG * 64];   // 36 KB (gemm)
    __shared__ int sd[2][256];           //  2 KB (scan)
    const int tid = threadIdx.x;

    if (blockIdx.x < SCAN_BLOCKS) {
        int gid4 = blockIdx.x * 256 + tid;
        int4 v = ((const int4*)cnt)[gid4];
        int s1 = v.x + v.y, s2 = s1 + v.z, s3 = s2 + v.w;
        sd[0][tid] = s3; __syncthreads();
        int cur = 0;
        for (int off = 1; off < 256; off <<= 1) {
            int nv = sd[cur][tid] + (tid >= off ? sd[cur][tid - off] : 0);
            sd[cur ^ 1][tid] = nv; __syncthreads();
            cur ^= 1;
        }
        int incl = sd[cur][tid];
        int eb = incl - s3;
        int4 w = make_int4(eb + v.x, eb + s1, eb + s2, eb + s3);
        ((int4*)inc)[gid4] = w;
        if (tid == 255) bsum[blockIdx.x] = incl;
        return;
    }

    // ---- gemm (operand-swapped MFMA; cvt_pk for all f32->bf16) ----
    {
        const float4* srcp = (const float4*)Wb;
        float4* dstp = (float4*)Bs;
        for (int i = tid; i < NFRAG * 64; i += 256) dstp[i] = srcp[i];
    }
    __syncthreads();

    const int lane  = tid & 63;
    const int rowIn = lane & 15;
    const int kgrp  = lane >> 4;
    int wid = ((blockIdx.x - SCAN_BLOCKS) * 256 + tid) >> 6;
    const int nw = GEMM_BLOCKS * 4;

    for (int rg = wid; rg < RG_TOTAL; rg += nw) {
        const int row0 = rg * 16;
        const float* hp = h + (size_t)(row0 + rowIn) * IN + kgrp * 8;

        short8v afr[4];
        #pragma unroll
        for (int ks = 0; ks < 4; ++ks) {
            float4 a0 = *(const float4*)(hp + ks * 32);
            float4 a1 = *(const float4*)(hp + ks * 32 + 4);
            uint4 u;
            u.x = cvtpk(a0.x, a0.y);
            u.y = cvtpk(a0.z, a0.w);
            u.z = cvtpk(a1.x, a1.y);
            u.w = cvtpk(a1.z, a1.w);
            afr[ks] = __builtin_bit_cast(short8v, u);
        }

        f32x4 acc[CT_ALL];
        #pragma unroll
        for (int ct = 0; ct < CT_ALL; ++ct) acc[ct] = (f32x4){0.f, 0.f, 0.f, 0.f};

        #pragma unroll
        for (int ks = 0; ks < 4; ++ks)
            #pragma unroll
            for (int ct = 0; ct < CT_ALL; ++ct)
                acc[ct] = __builtin_amdgcn_mfma_f32_16x16x32_bf16(
                    Bs[(ks * CT_ALL + ct) * 64 + lane], afr[ks], acc[ct], 0, 0, 0);

        const size_t zrow = (size_t)(row0 + rowIn) * HD;
        #pragma unroll
        for (int ct = 0; ct < 8; ++ct) {
            uint2 pk;
            pk.x = cvtpk(acc[ct][0], acc[ct][1]);
            pk.y = cvtpk(acc[ct][2], acc[ct][3]);
            *(uint2*)(z + zrow + ct * 16 + kgrp * 4) = pk;
        }
        {
            float4 v = make_float4(acc[8][0], acc[8][1], acc[8][2], acc[8][3]);
            int row = row0 + rowIn;
            if (kgrp < 2) *(float4*)(el + row * NH + kgrp * 4) = v;
            else          *(float4*)(er + row * NH + (kgrp - 2) * 4) = v;
        }
    }
}

// ---------------- merged scan2+scan3: offs only (no cursor needed anymore) ----------------
__global__ __launch_bounds__(256) void kscan23(
    const int* __restrict__ cnt, const int* __restrict__ inc, const int* __restrict__ bsum,
    int* __restrict__ offs)
{
    __shared__ int bs[2][128];
    const int tid = threadIdx.x;
    if (tid < 128) bs[0][tid] = (tid < SCAN_BLOCKS) ? bsum[tid] : 0;
    __syncthreads();
    int cur = 0;
    for (int off = 1; off < 128; off <<= 1) {
        if (tid < 128) {
            int nv = bs[cur][tid] + (tid >= off ? bs[cur][tid - off] : 0);
            bs[cur ^ 1][tid] = nv;
        }
        __syncthreads();
        cur ^= 1;
    }
    const int base = (blockIdx.x == 0) ? 0 : bs[cur][blockIdx.x - 1];

    int gid4 = blockIdx.x * 256 + tid;
    int4 c = ((const int4*)cnt)[gid4];
    int4 ic = ((const int4*)inc)[gid4];
    int i0 = gid4 * 4;
    int ex[4] = { base + ic.x - c.x, base + ic.y - c.y, base + ic.z - c.z, base + ic.w - c.w };
    #pragma unroll
    for (int j = 0; j < 4; ++j) {
        int i = i0 + j;
        if (i < NNODES) offs[i] = ex[j];
        else if (i == NNODES) offs[i] = NEDGES;
    }
}

// atomic-free scatter: pos = offs[d] + rank[e]
__global__ void k_scatter(const int* __restrict__ src, const int* __restrict__ dst,
                          const int* __restrict__ rank, const int* __restrict__ offs,
                          int* __restrict__ esrc) {
    int e0 = (blockIdx.x * blockDim.x + threadIdx.x) * 4;
    if (e0 >= NEDGES) return;
    int4 s4 = *(const int4*)(src + e0);
    int4 d4 = *(const int4*)(dst + e0);
    int4 r4 = *(const int4*)(rank + e0);
    esrc[offs[d4.x] + r4.x] = s4.x;
    esrc[offs[d4.y] + r4.y] = s4.y;
    esrc[offs[d4.z] + r4.z] = s4.z;
    esrc[offs[d4.w] + r4.w] = s4.w;
}

// ---------------- aggregate: one wave per node, 32 lanes per edge, 2 edges parallel ----------------
__global__ __launch_bounds__(256) void k_agg(
    const int* __restrict__ offs, const int* __restrict__ esrc,
    const float* __restrict__ el, const float* __restrict__ er,
    const unsigned short* __restrict__ z, const float* __restrict__ o,
    float* __restrict__ out)
{
    const int wid  = (blockIdx.x * blockDim.x + threadIdx.x) >> 6;
    const int lane = threadIdx.x & 63;
    if (wid >= NNODES) return;
    const int d  = wid;
    const int p0 = offs[d];
    const int n  = offs[d + 1] - p0;
    const int g  = lane & 31;
    const int e2 = lane >> 5;
    const int hh = g >> 2;
    const float el8 = el[d * NH + hh];

    const size_t obase = (size_t)d * HD + g * 4;
    const float4 ov = *(const float4*)(o + obase);

    float srun = 0.f;
    float4 acc = make_float4(0.f, 0.f, 0.f, 0.f);

    for (int c0 = 0; c0 < n; c0 += 64) {
        const int m = (n - c0 < 64) ? (n - c0) : 64;   // wave-uniform
        int sid = esrc[p0 + c0 + (lane < m ? lane : 0)];

        for (int b = 0; b < m; b += 8) {
            float erv[4]; uint2 zb[4];
            #pragma unroll
            for (int k = 0; k < 4; ++k) {
                int ei = b + k * 2 + e2;
                int eic = (ei < m) ? ei : 0;
                int s = __shfl(sid, eic, 64);
                erv[k] = er[s * NH + hh];
                zb[k]  = *(const uint2*)(z + (size_t)s * HD + g * 4);
            }
            #pragma unroll
            for (int k = 0; k < 4; ++k) {
                int ei = b + k * 2 + e2;
                float ev = el8 + erv[k];
                ev = fmaxf(ev, NEG_SLOPE * ev);
                float ex = (ei < m) ? __expf(ev) : 0.f;
                srun += ex;
                acc.x = fmaf(ex, bflo(zb[k].x), acc.x);
                acc.y = fmaf(ex, bfhi(zb[k].x), acc.y);
                acc.z = fmaf(ex, bflo(zb[k].y), acc.z);
                acc.w = fmaf(ex, bfhi(zb[k].y), acc.w);
            }
        }
    }

    srun  += __shfl_xor(srun, 32, 64);
    acc.x += __shfl_xor(acc.x, 32, 64);
    acc.y += __shfl_xor(acc.y, 32, 64);
    acc.z += __shfl_xor(acc.z, 32, 64);
    acc.w += __shfl_xor(acc.w, 32, 64);

    if (lane < 32) {
        float inv = (srun > 0.f) ? 1.f / srun : 0.f;
        float r0 = acc.x * inv, r1 = acc.y * inv, r2 = acc.z * inv, r3 = acc.w * inv;
        r0 = (r0 > 0.f) ? r0 : expm1f(r0);
        r1 = (r1 > 0.f) ? r1 : expm1f(r1);
        r2 = (r2 > 0.f) ? r2 : expm1f(r2);
        r3 = (r3 > 0.f) ? r3 : expm1f(r3);
        *(float4*)(out + obase) = make_float4(ov.x + r0, ov.y + r1, ov.z + r2, ov.w + r3);
    }
}

extern "C" void kernel_launch(void* const* d_in, const int* in_sizes, int n_in,
                              void* d_out, int out_size, void* d_ws, size_t ws_size,
                              hipStream_t stream) {
    const float* h      = (const float*)d_in[0];
    const float* o      = (const float*)d_in[1];
    const float* W      = (const float*)d_in[2];
    const float* attn_l = (const float*)d_in[3];
    const float* attn_r = (const float*)d_in[4];
    const int*   src    = (const int*)d_in[5];
    const int*   dst    = (const int*)d_in[6];
    float* out = (float*)d_out;

    char* ws = (char*)d_ws;
    unsigned short* z = (unsigned short*)(ws);         // 25,600,000 B (bf16)
    float* el     = (float*)(ws + 25600000);           //  3,200,000
    float* er     = (float*)(ws + 28800000);           //  3,200,000
    int*   cnt    = (int*)  (ws + 32000000);           //    401,408 (NPAD ints)
    int*   inc    = (int*)  (ws + 32401408);           //    401,408
    int*   offs   = (int*)  (ws + 32802816);           //    400,016
    int*   rank   = (int*)  (ws + 33202832);           //  2,400,000
    int*   bsum   = (int*)  (ws + 35602832);           //        512
    int*   esrc   = (int*)  (ws + 35603344);           //  2,400,000
    short8v* Wb   = (short8v*)(ws + 38003344);         //     36,864  (end ~38.04 MB)

    hipMemsetAsync(cnt, 0, NPAD * sizeof(int), stream);

    k_pack_hist<<<PACK_BLOCKS + HIST4_BLOCKS, 256, 0, stream>>>(W, attn_l, attn_r, Wb, dst, cnt, rank);
    k_gemm_scan1<<<SCAN_BLOCKS + GEMM_BLOCKS, 256, 0, stream>>>(h, Wb, z, el, er, cnt, inc, bsum);
    kscan23<<<SCAN_BLOCKS, 256, 0, stream>>>(cnt, inc, bsum, offs);
    k_scatter<<<(NEDGES / 4 + 255) / 256, 256, 0, stream>>>(src, dst, rank, offs, esrc);
    k_agg<<<(NNODES * 64 + 255) / 256, 256, 0, stream>>>(offs, esrc, el, er, z, o, out);
}